// Round 5
// baseline (322.053 us; speedup 1.0000x reference)
//
#include <hip/hip_runtime.h>
#include <math.h>

#define B_ 16
#define C_ 256
#define N_ 2048
#define D_ 64
#define NP_ 2080  // Vt row pitch (shorts): 2048+32 breaks 4KB power-of-2 channel stride

typedef __attribute__((ext_vector_type(8))) short bf8;  // 8 bf16 (4 VGPRs)
typedef __attribute__((ext_vector_type(4))) float f4;   // MFMA C/D

#define MFMA16(A, Bv, Cv) __builtin_amdgcn_mfma_f32_16x16x32_bf16(A, Bv, Cv, 0, 0, 0)

__device__ __forceinline__ short f2b(float f) {  // f32 -> bf16 RNE
  unsigned u = __float_as_uint(f);
  u = (u + 0x7fff + ((u >> 16) & 1)) >> 16;
  return (short)u;
}
__device__ __forceinline__ float b2f(short s) {
  return __uint_as_float(((unsigned)(unsigned short)s) << 16);
}

// ---------------- workspace layout (bytes), ~44 MB ----------------
static constexpr size_t OFF_XT = 0;                          // bf16 [B][N][C] 16 MB (later yT)
static constexpr size_t OFF_QN = (size_t)16 << 20;           // bf16 [B][N][64] 4 MB
static constexpr size_t OFF_KN = (size_t)20 << 20;           // bf16 [B][N][64] 4 MB
static constexpr size_t OFF_VT = (size_t)24 << 20;           // bf16 [B][C][NP_] 17.04 MB
static constexpr size_t OFF_CI = (size_t)42 << 20;           // f32 [B][N] 128 KB
static constexpr size_t OFF_WQ = OFF_CI + ((size_t)128 << 10);
static constexpr size_t OFF_WK = OFF_WQ + ((size_t)32 << 10);
static constexpr size_t OFF_WV = OFF_WK + ((size_t)32 << 10);
static constexpr size_t OFF_WP = OFF_WV + ((size_t)128 << 10);
static constexpr size_t OFF_S1 = OFF_WP + ((size_t)128 << 10);
static constexpr size_t OFF_S2 = OFF_S1 + 1024;
static constexpr size_t OFF_P1 = OFF_S2 + 4096;              // f32 [512][256] 512 KB
static constexpr size_t OFF_P2 = OFF_P1 + ((size_t)512 << 10);

// ---------------- x [B][C][N] f32 -> xT [B][N][C] bf16; z==16 slice packs weights ----------------
__global__ __launch_bounds__(256) void transpose_x_kernel(
    const float* __restrict__ x, short* __restrict__ xT,
    const float* __restrict__ fq, const float* __restrict__ fk,
    const float* __restrict__ fv, const float* __restrict__ fp,
    short* __restrict__ wq, short* __restrict__ wk,
    short* __restrict__ wv, short* __restrict__ wp) {
  if (blockIdx.z == 16) {  // weight-pack slice: 128 blocks x 256 thr x 5 elems = 163840
    int idx = (blockIdx.y * 32 + blockIdx.x) * 256 + threadIdx.x;
#pragma unroll
    for (int r = 0; r < 5; ++r) {
      int e = idx + r * 32768;
      if (e < 16384) wq[e] = f2b(fq[e]);
      else if (e < 32768) wk[e - 16384] = f2b(fk[e - 16384]);
      else if (e < 98304) wv[e - 32768] = f2b(fv[e - 32768]);
      else if (e < 163840) wp[e - 98304] = f2b(fp[e - 98304]);
    }
    return;
  }
  __shared__ float t[64][65];
  const int b = blockIdx.z, c0 = blockIdx.y * 64, n0 = blockIdx.x * 64;
  const int tid = threadIdx.x;
  const float* xp = x + ((size_t)b * C_ + c0) * N_ + n0;
#pragma unroll
  for (int i = 0; i < 16; ++i) {
    int idx = tid + i * 256;
    int cl = idx >> 6, nl = idx & 63;
    t[cl][nl] = xp[(size_t)cl * N_ + nl];
  }
  __syncthreads();
  short* op = xT + ((size_t)b * N_ + n0) * C_ + c0;
#pragma unroll
  for (int i = 0; i < 8; ++i) {
    int idx = tid + i * 256;
    int nl = idx >> 5, cl2 = (idx & 31) * 2;
    ushort2 v;
    v.x = (unsigned short)f2b(t[cl2][nl]);
    v.y = (unsigned short)f2b(t[cl2 + 1][nl]);
    *(ushort2*)(op + (size_t)nl * C_ + cl2) = v;
  }
}

// ---------------- fused projection GEMM: z=0 -> Q, z=1 -> K, z=2..5 -> V ----------------
// Q/K: out[b][n][64]; V: out[b][o][NP_] (pitch NP_). xT read once for all three.
__global__ __launch_bounds__(256, 4) void proj_all_kernel(
    const short* __restrict__ xT, const short* __restrict__ Wqb,
    const short* __restrict__ Wkb, const short* __restrict__ Wvb,
    short* __restrict__ Qn, short* __restrict__ Kn, short* __restrict__ Vt) {
  const int tid = threadIdx.x;
  const int wv = tid >> 6, lane = tid & 63;
  const int li = lane & 15, quad = lane >> 4;
  const int z = blockIdx.z;
  const short* W;
  short* out;
  int o0;
  bool outt;
  if (z == 0) { W = Wqb; out = Qn; o0 = 0; outt = true; }
  else if (z == 1) { W = Wkb; out = Kn; o0 = 0; outt = true; }
  else { W = Wvb; out = Vt; o0 = (z - 2) * 64; outt = false; }
  const int b = blockIdx.y, n0 = blockIdx.x * 64;
  const int n = n0 + wv * 16 + li;
  const short* xrow = xT + ((size_t)b * N_ + n) * C_ + quad * 8;
  f4 acc[4] = {};
  for (int ks = 0; ks < 8; ++ks) {
    bf8 bfr = *(const bf8*)(xrow + ks * 32);
#pragma unroll
    for (int ot = 0; ot < 4; ++ot) {
      bf8 afr = *(const bf8*)(W + (size_t)(o0 + ot * 16 + li) * C_ + ks * 32 + quad * 8);
      acc[ot] = MFMA16(afr, bfr, acc[ot]);
    }
  }
  if (outt) {
#pragma unroll
    for (int ot = 0; ot < 4; ++ot) {
      short4 v = {f2b(acc[ot].x), f2b(acc[ot].y), f2b(acc[ot].z), f2b(acc[ot].w)};
      *(short4*)(out + ((size_t)b * N_ + n) * D_ + ot * 16 + quad * 4) = v;
    }
  } else {
#pragma unroll
    for (int ot = 0; ot < 4; ++ot) {
#pragma unroll
      for (int r = 0; r < 4; ++r) {
        out[((size_t)b * C_ + o0 + ot * 16 + quad * 4 + r) * NP_ + n] = f2b(acc[ot][r]);
      }
    }
  }
}

// ---------------- pass 1: cinv[b][m] = 1 / sum_n exp(energy[n][m]) ----------------
// Q staged in LDS per block (once), double-buffered; K strip per wave held in regs.
__global__ __launch_bounds__(256, 2) void colstats_kernel(const short* __restrict__ Qn,
                                                          const short* __restrict__ Kn,
                                                          float* __restrict__ cinv) {
  __shared__ short qS[2][64][72];
  const int tid = threadIdx.x;
  const int wv = tid >> 6, lane = tid & 63;
  const int li = lane & 15, quad = lane >> 4;
  const int b = blockIdx.y, m0 = blockIdx.x * 64;
  const short* krow = Kn + ((size_t)b * N_ + m0 + wv * 16 + li) * D_ + quad * 8;
  bf8 af0 = *(const bf8*)(krow);
  bf8 af1 = *(const bf8*)(krow + 32);
  const short* Qb = Qn + (size_t)b * N_ * D_;
  // stage chunk 0
#pragma unroll
  for (int j = 0; j < 2; ++j) {
    int idx = tid * 2 + j;
    int row = idx >> 3, c8 = (idx & 7) * 8;
    *(bf8*)&qS[0][row][c8] = *(const bf8*)(Qb + (size_t)row * D_ + c8);
  }
  __syncthreads();
  float csum[4] = {0.f, 0.f, 0.f, 0.f};
  for (int t = 0; t < 32; ++t) {
    if (t < 31) {
#pragma unroll
      for (int j = 0; j < 2; ++j) {
        int idx = tid * 2 + j;
        int row = idx >> 3, c8 = (idx & 7) * 8;
        *(bf8*)&qS[(t + 1) & 1][row][c8] =
            *(const bf8*)(Qb + (size_t)((t + 1) * 64 + row) * D_ + c8);
      }
    }
#pragma unroll
    for (int nt = 0; nt < 4; ++nt) {
      bf8 b0 = *(const bf8*)&qS[t & 1][nt * 16 + li][quad * 8];
      bf8 b1 = *(const bf8*)&qS[t & 1][nt * 16 + li][32 + quad * 8];
      f4 s = {};
      s = MFMA16(af0, b0, s);
      s = MFMA16(af1, b1, s);
      csum[0] += __expf(s.x);
      csum[1] += __expf(s.y);
      csum[2] += __expf(s.z);
      csum[3] += __expf(s.w);
    }
    __syncthreads();
  }
#pragma unroll
  for (int r = 0; r < 4; ++r) {
#pragma unroll
    for (int m = 1; m < 16; m <<= 1) csum[r] += __shfl_xor(csum[r], m);
  }
  if (li == 0) {
#pragma unroll
    for (int r = 0; r < 4; ++r)
      cinv[(size_t)b * N_ + m0 + wv * 16 + quad * 4 + r] = 1.f / csum[r];
  }
}

// ---------------- pass 2: attention + fsa + y = x - fsa (-> yT bf16) ----------------
// 512 thr, n-tile 64, m-iter 128, grid (32,16) = 512 blocks -> 2 blocks/CU.
// S phase: m-split (wave wv owns m-strip wv*16). PV phase: o-split (wave owns 32 o).
// Wave phase-stagger: even waves run S(t+1) -> PV(t), odd waves PV(t) -> S(t+1),
// so at any instant ~half the waves feed the VALU (exp/cvt) and half the MFMA pipe.
// K prefetched 2 epochs ahead so even waves' S never waits on the K load.
__global__ __launch_bounds__(512, 2) void attn_fsa_kernel(
    const float* __restrict__ x, const short* __restrict__ Qn, const short* __restrict__ Kn,
    const short* __restrict__ Vt, const float* __restrict__ cinv, short* __restrict__ yT) {
  __shared__ short pT[2][64][136];  // [buf][n][m], pitch 136
  __shared__ float civS[2048];
  __shared__ float racc[64];
  const int tid = threadIdx.x;
  const int wv = tid >> 6, lane = tid & 63;
  const int li = lane & 15, quad = lane >> 4;
  const int b = blockIdx.y, n0 = blockIdx.x * 64;
  // stage civ + zero racc
  *(float4*)(civS + tid * 4) = *(const float4*)(cinv + (size_t)b * N_ + tid * 4);
  if (tid < 64) racc[tid] = 0.f;
  // Q B-frags for all 4 n-tiles (held in regs for the whole kernel)
  bf8 q[4][2];
#pragma unroll
  for (int nt = 0; nt < 4; ++nt) {
    const short* qrow = Qn + ((size_t)b * N_ + n0 + nt * 16 + li) * D_ + quad * 8;
    q[nt][0] = *(const bf8*)(qrow);
    q[nt][1] = *(const bf8*)(qrow + 32);
  }
  __syncthreads();
  f4 acc[2][4] = {};     // [ot][nt]: o = wv*32+ot*16+quad*4+r, n = n0+nt*16+li
  float rloc[4] = {};    // per-lane partial row sums, per nt
  const int ob = wv * 32;
  const short* Kb = Kn + (size_t)b * N_ * D_;
  const short* Vb = Vt + (size_t)b * C_ * NP_;

  // S-phase: energy for m-strip [t1*128 + wv*16, +16), all 4 n-tiles -> pT[t1&1]
  auto do_s = [&](int t1, bf8 a0, bf8 a1) {
    f4 civ4 = *(const f4*)(civS + t1 * 128 + wv * 16 + quad * 4);
    short* Pw = &pT[t1 & 1][0][0];
#pragma unroll
    for (int nt = 0; nt < 4; ++nt) {
      f4 s = {};
      s = MFMA16(a0, q[nt][0], s);
      s = MFMA16(a1, q[nt][1], s);
      short4 pv;
#pragma unroll
      for (int r = 0; r < 4; ++r) {
        float p = __expf(s[r]) * civ4[r];
        short ph = f2b(p);
        ((short*)&pv)[r] = ph;
        rloc[nt] += b2f(ph);
      }
      *(short4*)(Pw + (size_t)(nt * 16 + li) * 136 + wv * 16 + quad * 4) = pv;
    }
  };

  // ---- prologue: S(0) -> buf0 ----
  {
    const short* krow = Kb + (size_t)(wv * 16 + li) * D_ + quad * 8;
    bf8 a0 = *(const bf8*)(krow);
    bf8 a1 = *(const bf8*)(krow + 32);
    do_s(0, a0, a1);
  }
  // ---- V(0) prefetch ----
  bf8 va[2][4];
#pragma unroll
  for (int ot = 0; ot < 2; ++ot)
#pragma unroll
    for (int kf = 0; kf < 4; ++kf)
      va[ot][kf] = *(const bf8*)(Vb + (size_t)(ob + ot * 16 + li) * NP_ + kf * 32 + quad * 8);
  // ---- K(1) prefetch (2-ahead discipline) ----
  bf8 ka0, ka1;
  {
    const short* krow = Kb + (size_t)(128 + wv * 16 + li) * D_ + quad * 8;
    ka0 = *(const bf8*)(krow);
    ka1 = *(const bf8*)(krow + 32);
  }
  __syncthreads();

  for (int t = 0; t < 16; ++t) {
    const int mm2 = (t + 1) * 128;
    bf8 vn[2][4], kn0, kn1;
    if (t < 15) {
#pragma unroll
      for (int ot = 0; ot < 2; ++ot)
#pragma unroll
        for (int kf = 0; kf < 4; ++kf)
          vn[ot][kf] = *(const bf8*)(Vb + (size_t)(ob + ot * 16 + li) * NP_ +
                                     mm2 + kf * 32 + quad * 8);
    }
    if (t < 14) {
      const short* krow = Kb + (size_t)((t + 2) * 128 + wv * 16 + li) * D_ + quad * 8;
      kn0 = *(const bf8*)(krow);
      kn1 = *(const bf8*)(krow + 32);
    }
    // PV(t): reads pT[t&1] + va
    auto do_pv = [&]() {
      const short* Pb = &pT[t & 1][0][0];
#pragma unroll
      for (int nt = 0; nt < 4; ++nt) {
#pragma unroll
        for (int kf = 0; kf < 4; ++kf) {
          bf8 pb = *(const bf8*)(Pb + (size_t)(nt * 16 + li) * 136 + kf * 32 + quad * 8);
#pragma unroll
          for (int ot = 0; ot < 2; ++ot) acc[ot][nt] = MFMA16(va[ot][kf], pb, acc[ot][nt]);
        }
      }
    };
    if (wv & 1) {
      do_pv();
      if (t < 15) do_s(t + 1, ka0, ka1);
    } else {
      if (t < 15) do_s(t + 1, ka0, ka1);
      do_pv();
    }
    if (t < 15) {
#pragma unroll
      for (int ot = 0; ot < 2; ++ot)
#pragma unroll
        for (int kf = 0; kf < 4; ++kf) va[ot][kf] = vn[ot][kf];
    }
    if (t < 14) {
      ka0 = kn0;
      ka1 = kn1;
    }
    __syncthreads();
  }
  // ---- row-sum reduction: quad-shfl then cross-wave LDS atomics ----
#pragma unroll
  for (int nt = 0; nt < 4; ++nt) {
    float rv = rloc[nt];
    rv += __shfl_xor(rv, 16);
    rv += __shfl_xor(rv, 32);
    if (quad == 0) atomicAdd(&racc[nt * 16 + li], rv);
  }
  __syncthreads();
  // ---- epilogue: y = x - fsa / rsum ----
#pragma unroll
  for (int nt = 0; nt < 4; ++nt) {
    const int nn = n0 + nt * 16 + li;
    const float rinv = 1.f / (1e-9f + racc[nt * 16 + li]);
    short* yrow = yT + ((size_t)b * N_ + nn) * C_ + ob;
#pragma unroll
    for (int ot = 0; ot < 2; ++ot) {
      short4 v;
#pragma unroll
      for (int r = 0; r < 4; ++r) {
        int o = ob + ot * 16 + quad * 4 + r;
        float xv = x[((size_t)b * C_ + o) * N_ + nn];
        ((short*)&v)[r] = f2b(xv - acc[ot][nt][r] * rinv);
      }
      *(short4*)(yrow + ot * 16 + quad * 4) = v;
    }
  }
}

// ---------------- h = Wp . y -> H (=d_out) f32 + per-block BN partials ----------------
__global__ __launch_bounds__(256, 4) void wp_kernel(const short* __restrict__ yT,
                                                    const short* __restrict__ Wp,
                                                    float* __restrict__ H,
                                                    float* __restrict__ P1,
                                                    float* __restrict__ P2) {
  __shared__ alignas(16) float ha[64][68];
  __shared__ float red1[64][4];
  __shared__ float red2[64][4];
  const int tid = threadIdx.x;
  const int wv = tid >> 6, lane = tid & 63;
  const int li = lane & 15, quad = lane >> 4;
  const int b = blockIdx.y, n0 = blockIdx.x * 64, o0 = blockIdx.z * 64;
  const int n = n0 + wv * 16 + li;
  const short* yrow = yT + ((size_t)b * N_ + n) * C_ + quad * 8;
  f4 acc[4] = {};
  for (int ks = 0; ks < 8; ++ks) {
    bf8 bfr = *(const bf8*)(yrow + ks * 32);
#pragma unroll
    for (int ot = 0; ot < 4; ++ot) {
      bf8 afr = *(const bf8*)(Wp + (size_t)(o0 + ot * 16 + li) * C_ + ks * 32 + quad * 8);
      acc[ot] = MFMA16(afr, bfr, acc[ot]);
    }
  }
#pragma unroll
  for (int ot = 0; ot < 4; ++ot)
#pragma unroll
    for (int r = 0; r < 4; ++r) ha[ot * 16 + quad * 4 + r][wv * 16 + li] = acc[ot][r];
  __syncthreads();
  const int o = tid >> 2, nq = tid & 3;
  float s1p = 0.f, s2p = 0.f;
  float* hrow = H + ((size_t)b * C_ + o0 + o) * N_ + n0 + nq * 16;
#pragma unroll
  for (int j4 = 0; j4 < 4; ++j4) {
    float4 v = *reinterpret_cast<const float4*>(&ha[o][nq * 16 + j4 * 4]);
    s1p += v.x + v.y + v.z + v.w;
    s2p += v.x * v.x + v.y * v.y + v.z * v.z + v.w * v.w;
    reinterpret_cast<float4*>(hrow)[j4] = v;
  }
  red1[o][nq] = s1p;
  red2[o][nq] = s2p;
  __syncthreads();
  if (tid < 64) {
    float a1 = red1[tid][0] + red1[tid][1] + red1[tid][2] + red1[tid][3];
    float a2 = red2[tid][0] + red2[tid][1] + red2[tid][2] + red2[tid][3];
    const int g = b * 32 + blockIdx.x;
    P1[(size_t)g * 256 + o0 + tid] = a1;
    P2[(size_t)g * 256 + o0 + tid] = a2;
  }
}

// ---------------- fold partials: no atomics, direct write ----------------
// grid(16) x 256 thr: block owns 16 channels; 16 lanes per channel sum 512 groups.
__global__ __launch_bounds__(256) void bn_reduce_kernel(const float* __restrict__ P1,
                                                        const float* __restrict__ P2,
                                                        float* __restrict__ S1,
                                                        float* __restrict__ S2) {
  const int lc = threadIdx.x >> 4, gl = threadIdx.x & 15;
  const int c = blockIdx.x * 16 + lc;
  float a1 = 0.f, a2 = 0.f;
#pragma unroll
  for (int k = 0; k < 32; ++k) {
    int g = gl + k * 16;
    a1 += P1[(size_t)g * 256 + c];
    a2 += P2[(size_t)g * 256 + c];
  }
#pragma unroll
  for (int m = 1; m < 16; m <<= 1) {
    a1 += __shfl_xor(a1, m);
    a2 += __shfl_xor(a2, m);
  }
  if (gl == 0) {
    S1[c] = a1;
    S2[c] = a2;
  }
}

// ---------------- BN apply (affine terms computed inline from S1/S2) ----------------
__global__ __launch_bounds__(256) void bn_apply_kernel(const float* __restrict__ H,
                                                       const float* __restrict__ x,
                                                       const float* __restrict__ S1,
                                                       const float* __restrict__ S2,
                                                       const float* __restrict__ gamma,
                                                       const float* __restrict__ beta,
                                                       float* __restrict__ out) {
  size_t idx = ((size_t)blockIdx.x * 256 + threadIdx.x) * 4;
  int o = (int)((idx >> 11) & 255);
  const float invn = 1.f / ((float)B_ * N_);
  float mean = S1[o] * invn;
  float var = S2[o] * invn - mean * mean;
  float inv = rsqrtf(var + 1e-5f);
  float a = gamma[o] * inv;
  float c = beta[o] - mean * a;
  float4 h = *reinterpret_cast<const float4*>(&H[idx]);
  float4 xv = *reinterpret_cast<const float4*>(&x[idx]);
  float4 r;
  r.x = fmaxf(h.x * a + c, 0.f) + xv.x;
  r.y = fmaxf(h.y * a + c, 0.f) + xv.y;
  r.z = fmaxf(h.z * a + c, 0.f) + xv.z;
  r.w = fmaxf(h.w * a + c, 0.f) + xv.w;
  *reinterpret_cast<float4*>(&out[idx]) = r;
}

extern "C" void kernel_launch(void* const* d_in, const int* in_sizes, int n_in,
                              void* d_out, int out_size, void* d_ws, size_t ws_size,
                              hipStream_t stream) {
  (void)in_sizes; (void)n_in; (void)out_size; (void)ws_size;
  const float* x = (const float*)d_in[0];
  const float* Wq = (const float*)d_in[1];
  const float* Wk = (const float*)d_in[2];
  const float* Wv = (const float*)d_in[3];
  const float* Wp = (const float*)d_in[4];
  const float* gamma = (const float*)d_in[5];
  const float* beta = (const float*)d_in[6];
  char* ws = (char*)d_ws;
  short* xT = (short*)(ws + OFF_XT);
  short* Qn = (short*)(ws + OFF_QN);
  short* Kn = (short*)(ws + OFF_KN);
  short* Vt = (short*)(ws + OFF_VT);
  float* CI = (float*)(ws + OFF_CI);
  short* Wqb = (short*)(ws + OFF_WQ);
  short* Wkb = (short*)(ws + OFF_WK);
  short* Wvb = (short*)(ws + OFF_WV);
  short* Wpb = (short*)(ws + OFF_WP);
  float* S1 = (float*)(ws + OFF_S1);
  float* S2 = (float*)(ws + OFF_S2);
  float* P1 = (float*)(ws + OFF_P1);
  float* P2 = (float*)(ws + OFF_P2);
  short* yT = xT;            // reuse xT region (dead after projections)
  float* out = (float*)d_out;
  float* H = out;            // H staged in d_out; bn_apply rewrites in place

  dim3 blk(256);
  transpose_x_kernel<<<dim3(32, 4, 17), blk, 0, stream>>>(x, xT, Wq, Wk, Wv, Wp,
                                                          Wqb, Wkb, Wvb, Wpb);
  proj_all_kernel<<<dim3(32, 16, 6), blk, 0, stream>>>(xT, Wqb, Wkb, Wvb, Qn, Kn, Vt);
  colstats_kernel<<<dim3(32, 16), blk, 0, stream>>>(Qn, Kn, CI);
  attn_fsa_kernel<<<dim3(32, 16), dim3(512), 0, stream>>>(x, Qn, Kn, Vt, CI, yT);
  wp_kernel<<<dim3(32, 16, 4), blk, 0, stream>>>(yT, Wpb, H, P1, P2);
  bn_reduce_kernel<<<dim3(16), blk, 0, stream>>>(P1, P2, S1, S2);
  bn_apply_kernel<<<dim3(8192), blk, 0, stream>>>(H, x, S1, S2, gamma, beta, out);
}

// Round 7
// 304.512 us; speedup vs baseline: 1.0576x; 1.0576x over previous
//
#include <hip/hip_runtime.h>
#include <math.h>

#define B_ 16
#define C_ 256
#define N_ 2048
#define D_ 64
#define NP_ 2080  // Vt row pitch (shorts): 2048+32 breaks 4KB power-of-2 channel stride

typedef __attribute__((ext_vector_type(8))) short bf8;  // 8 bf16 (4 VGPRs)
typedef __attribute__((ext_vector_type(4))) float f4;   // MFMA C/D

#define MFMA16(A, Bv, Cv) __builtin_amdgcn_mfma_f32_16x16x32_bf16(A, Bv, Cv, 0, 0, 0)

__device__ __forceinline__ short f2b(float f) {  // f32 -> bf16 RNE
  unsigned u = __float_as_uint(f);
  u = (u + 0x7fff + ((u >> 16) & 1)) >> 16;
  return (short)u;
}
__device__ __forceinline__ float b2f(short s) {
  return __uint_as_float(((unsigned)(unsigned short)s) << 16);
}

// ---------------- workspace layout (bytes), ~44 MB ----------------
static constexpr size_t OFF_XT = 0;                          // bf16 [B][N][C] 16 MB (later yT)
static constexpr size_t OFF_QN = (size_t)16 << 20;           // bf16 [B][N][64] 4 MB
static constexpr size_t OFF_KN = (size_t)20 << 20;           // bf16 [B][N][64] 4 MB
static constexpr size_t OFF_VT = (size_t)24 << 20;           // bf16 [B][C][NP_] 17.04 MB
static constexpr size_t OFF_CI = (size_t)42 << 20;           // f32 [B][N] 128 KB
static constexpr size_t OFF_WQ = OFF_CI + ((size_t)128 << 10);
static constexpr size_t OFF_WK = OFF_WQ + ((size_t)32 << 10);
static constexpr size_t OFF_WV = OFF_WK + ((size_t)32 << 10);
static constexpr size_t OFF_WP = OFF_WV + ((size_t)128 << 10);
static constexpr size_t OFF_S1 = OFF_WP + ((size_t)128 << 10);
static constexpr size_t OFF_S2 = OFF_S1 + 1024;
static constexpr size_t OFF_P1 = OFF_S2 + 4096;              // f32 [512][256] 512 KB
static constexpr size_t OFF_P2 = OFF_P1 + ((size_t)512 << 10);

// ---------------- x [B][C][N] f32 -> xT [B][N][C] bf16; z==16 slice packs weights ----------------
__global__ __launch_bounds__(256) void transpose_x_kernel(
    const float* __restrict__ x, short* __restrict__ xT,
    const float* __restrict__ fq, const float* __restrict__ fk,
    const float* __restrict__ fv, const float* __restrict__ fp,
    short* __restrict__ wq, short* __restrict__ wk,
    short* __restrict__ wv, short* __restrict__ wp) {
  if (blockIdx.z == 16) {  // weight-pack slice: 128 blocks x 256 thr x 5 elems = 163840
    int idx = (blockIdx.y * 32 + blockIdx.x) * 256 + threadIdx.x;
#pragma unroll
    for (int r = 0; r < 5; ++r) {
      int e = idx + r * 32768;
      if (e < 16384) wq[e] = f2b(fq[e]);
      else if (e < 32768) wk[e - 16384] = f2b(fk[e - 16384]);
      else if (e < 98304) wv[e - 32768] = f2b(fv[e - 32768]);
      else if (e < 163840) wp[e - 98304] = f2b(fp[e - 98304]);
    }
    return;
  }
  __shared__ float t[64][65];
  const int b = blockIdx.z, c0 = blockIdx.y * 64, n0 = blockIdx.x * 64;
  const int tid = threadIdx.x;
  const float* xp = x + ((size_t)b * C_ + c0) * N_ + n0;
#pragma unroll
  for (int i = 0; i < 16; ++i) {
    int idx = tid + i * 256;
    int cl = idx >> 6, nl = idx & 63;
    t[cl][nl] = xp[(size_t)cl * N_ + nl];
  }
  __syncthreads();
  short* op = xT + ((size_t)b * N_ + n0) * C_ + c0;
#pragma unroll
  for (int i = 0; i < 8; ++i) {
    int idx = tid + i * 256;
    int nl = idx >> 5, cl2 = (idx & 31) * 2;
    ushort2 v;
    v.x = (unsigned short)f2b(t[cl2][nl]);
    v.y = (unsigned short)f2b(t[cl2 + 1][nl]);
    *(ushort2*)(op + (size_t)nl * C_ + cl2) = v;
  }
}

// ---------------- projection GEMM, z=0: Q+K, z=1: V(4 tiles) ----------------
// One xT read feeds 8 (z=0) or 16 (z=1) MFMA tiles -> xT streamed 2x total, not 6x.
// V pass split into two 8-acc halves to keep VGPR under the (256,4) budget.
__global__ __launch_bounds__(256, 4) void proj_qkv_kernel(
    const short* __restrict__ xT, const short* __restrict__ Wqb,
    const short* __restrict__ Wkb, const short* __restrict__ Wvb,
    short* __restrict__ Qn, short* __restrict__ Kn, short* __restrict__ Vt) {
  const int tid = threadIdx.x;
  const int wv = tid >> 6, lane = tid & 63;
  const int li = lane & 15, quad = lane >> 4;
  const int b = blockIdx.y, n0 = blockIdx.x * 64;
  const int n = n0 + wv * 16 + li;
  const short* xrow = xT + ((size_t)b * N_ + n) * C_ + quad * 8;
  if (blockIdx.z == 0) {  // ---- Q and K ----
    f4 accq[4] = {}, acck[4] = {};
    for (int ks = 0; ks < 8; ++ks) {
      bf8 bfr = *(const bf8*)(xrow + ks * 32);
#pragma unroll
      for (int ot = 0; ot < 4; ++ot) {
        bf8 aq = *(const bf8*)(Wqb + (size_t)(ot * 16 + li) * C_ + ks * 32 + quad * 8);
        accq[ot] = MFMA16(aq, bfr, accq[ot]);
        bf8 ak = *(const bf8*)(Wkb + (size_t)(ot * 16 + li) * C_ + ks * 32 + quad * 8);
        acck[ot] = MFMA16(ak, bfr, acck[ot]);
      }
    }
#pragma unroll
    for (int ot = 0; ot < 4; ++ot) {
      short4 vq = {f2b(accq[ot].x), f2b(accq[ot].y), f2b(accq[ot].z), f2b(accq[ot].w)};
      *(short4*)(Qn + ((size_t)b * N_ + n) * D_ + ot * 16 + quad * 4) = vq;
      short4 vk = {f2b(acck[ot].x), f2b(acck[ot].y), f2b(acck[ot].z), f2b(acck[ot].w)};
      *(short4*)(Kn + ((size_t)b * N_ + n) * D_ + ot * 16 + quad * 4) = vk;
    }
  } else {  // ---- V: o = 0..255 in two halves of 128 ----
#pragma unroll
    for (int half = 0; half < 2; ++half) {
      f4 accv[2][4] = {};  // [vt][ot]
      for (int ks = 0; ks < 8; ++ks) {
        bf8 bfr = *(const bf8*)(xrow + ks * 32);
#pragma unroll
        for (int vt = 0; vt < 2; ++vt)
#pragma unroll
          for (int ot = 0; ot < 4; ++ot) {
            bf8 av = *(const bf8*)(Wvb + (size_t)((half * 2 + vt) * 64 + ot * 16 + li) * C_ +
                                   ks * 32 + quad * 8);
            accv[vt][ot] = MFMA16(av, bfr, accv[vt][ot]);
          }
      }
#pragma unroll
      for (int vt = 0; vt < 2; ++vt)
#pragma unroll
        for (int ot = 0; ot < 4; ++ot)
#pragma unroll
          for (int r = 0; r < 4; ++r)
            Vt[((size_t)b * C_ + (half * 2 + vt) * 64 + ot * 16 + quad * 4 + r) * NP_ + n] =
                f2b(accv[vt][ot][r]);
    }
  }
}

// ---------------- pass 1: cinv[b][m] = 1 / sum_n exp(energy[n][m]) ----------------
// Q staged in LDS per block (once), double-buffered; K strip per wave held in regs.
__global__ __launch_bounds__(256, 2) void colstats_kernel(const short* __restrict__ Qn,
                                                          const short* __restrict__ Kn,
                                                          float* __restrict__ cinv) {
  __shared__ short qS[2][64][72];
  const int tid = threadIdx.x;
  const int wv = tid >> 6, lane = tid & 63;
  const int li = lane & 15, quad = lane >> 4;
  const int b = blockIdx.y, m0 = blockIdx.x * 64;
  const short* krow = Kn + ((size_t)b * N_ + m0 + wv * 16 + li) * D_ + quad * 8;
  bf8 af0 = *(const bf8*)(krow);
  bf8 af1 = *(const bf8*)(krow + 32);
  const short* Qb = Qn + (size_t)b * N_ * D_;
  // stage chunk 0
#pragma unroll
  for (int j = 0; j < 2; ++j) {
    int idx = tid * 2 + j;
    int row = idx >> 3, c8 = (idx & 7) * 8;
    *(bf8*)&qS[0][row][c8] = *(const bf8*)(Qb + (size_t)row * D_ + c8);
  }
  __syncthreads();
  float csum[4] = {0.f, 0.f, 0.f, 0.f};
  for (int t = 0; t < 32; ++t) {
    if (t < 31) {
#pragma unroll
      for (int j = 0; j < 2; ++j) {
        int idx = tid * 2 + j;
        int row = idx >> 3, c8 = (idx & 7) * 8;
        *(bf8*)&qS[(t + 1) & 1][row][c8] =
            *(const bf8*)(Qb + (size_t)((t + 1) * 64 + row) * D_ + c8);
      }
    }
#pragma unroll
    for (int nt = 0; nt < 4; ++nt) {
      bf8 b0 = *(const bf8*)&qS[t & 1][nt * 16 + li][quad * 8];
      bf8 b1 = *(const bf8*)&qS[t & 1][nt * 16 + li][32 + quad * 8];
      f4 s = {};
      s = MFMA16(af0, b0, s);
      s = MFMA16(af1, b1, s);
      csum[0] += __expf(s.x);
      csum[1] += __expf(s.y);
      csum[2] += __expf(s.z);
      csum[3] += __expf(s.w);
    }
    __syncthreads();
  }
#pragma unroll
  for (int r = 0; r < 4; ++r) {
#pragma unroll
    for (int m = 1; m < 16; m <<= 1) csum[r] += __shfl_xor(csum[r], m);
  }
  if (li == 0) {
#pragma unroll
    for (int r = 0; r < 4; ++r)
      cinv[(size_t)b * N_ + m0 + wv * 16 + quad * 4 + r] = 1.f / csum[r];
  }
}

// ---------------- pass 2: attention + fsa + y = x - fsa (-> yT bf16) ----------------
// 512 thr, n-tile 64, m-iter 128, grid (32,16) = 512 blocks -> 2 blocks/CU.
// S phase: m-split (wave wv owns m-strip wv*16). PV phase: o-split (wave owns 32 o).
// Pipelined: epoch t = [prefetch K/V(t+1); PV(t); S(t+1)], 2 pT bufs, one barrier/epoch.
// NOTE r5 lesson: no phase-stagger / deep prefetch — VGPR must stay ~64 for occupancy.
__global__ __launch_bounds__(512, 2) void attn_fsa_kernel(
    const float* __restrict__ x, const short* __restrict__ Qn, const short* __restrict__ Kn,
    const short* __restrict__ Vt, const float* __restrict__ cinv, short* __restrict__ yT) {
  __shared__ short pT[2][64][136];  // [buf][n][m], pitch 136
  __shared__ float civS[2048];
  __shared__ float racc[64];
  const int tid = threadIdx.x;
  const int wv = tid >> 6, lane = tid & 63;
  const int li = lane & 15, quad = lane >> 4;
  const int b = blockIdx.y, n0 = blockIdx.x * 64;
  // stage civ + zero racc
  *(float4*)(civS + tid * 4) = *(const float4*)(cinv + (size_t)b * N_ + tid * 4);
  if (tid < 64) racc[tid] = 0.f;
  // Q B-frags for all 4 n-tiles (held in regs for the whole kernel)
  bf8 q[4][2];
#pragma unroll
  for (int nt = 0; nt < 4; ++nt) {
    const short* qrow = Qn + ((size_t)b * N_ + n0 + nt * 16 + li) * D_ + quad * 8;
    q[nt][0] = *(const bf8*)(qrow);
    q[nt][1] = *(const bf8*)(qrow + 32);
  }
  __syncthreads();
  f4 acc[2][4] = {};     // [ot][nt]: o = wv*32+ot*16+quad*4+r, n = n0+nt*16+li
  float rloc[4] = {};    // per-lane partial row sums, per nt
  const int ob = wv * 32;
  const short* Kb = Kn + (size_t)b * N_ * D_;
  const short* Vb = Vt + (size_t)b * C_ * NP_;
  // ---- prologue: S(0) -> buf0 ----
  {
    const short* krow = Kb + (size_t)(wv * 16 + li) * D_ + quad * 8;
    bf8 a0 = *(const bf8*)(krow);
    bf8 a1 = *(const bf8*)(krow + 32);
    f4 civ4 = *(const f4*)(civS + wv * 16 + quad * 4);
#pragma unroll
    for (int nt = 0; nt < 4; ++nt) {
      f4 s = {};
      s = MFMA16(a0, q[nt][0], s);
      s = MFMA16(a1, q[nt][1], s);
      short4 pv;
#pragma unroll
      for (int r = 0; r < 4; ++r) {
        float p = __expf(s[r]) * civ4[r];
        short ph = f2b(p);
        ((short*)&pv)[r] = ph;
        rloc[nt] += b2f(ph);
      }
      *(short4*)&pT[0][nt * 16 + li][wv * 16 + quad * 4] = pv;
    }
  }
  // ---- V(0) prefetch ----
  bf8 va[2][4];
#pragma unroll
  for (int ot = 0; ot < 2; ++ot)
#pragma unroll
    for (int kf = 0; kf < 4; ++kf)
      va[ot][kf] = *(const bf8*)(Vb + (size_t)(ob + ot * 16 + li) * NP_ + kf * 32 + quad * 8);
  __syncthreads();
  for (int t = 0; t < 16; ++t) {
    const int mm2 = (t + 1) * 128;
    bf8 vn[2][4], a0, a1;
    if (t < 15) {
#pragma unroll
      for (int ot = 0; ot < 2; ++ot)
#pragma unroll
        for (int kf = 0; kf < 4; ++kf)
          vn[ot][kf] = *(const bf8*)(Vb + (size_t)(ob + ot * 16 + li) * NP_ +
                                     mm2 + kf * 32 + quad * 8);
      const short* krow = Kb + (size_t)(mm2 + wv * 16 + li) * D_ + quad * 8;
      a0 = *(const bf8*)(krow);
      a1 = *(const bf8*)(krow + 32);
    }
    // ---- PV(t): reads pT[t&1] + va ----
    const short* Pb = &pT[t & 1][0][0];
#pragma unroll
    for (int nt = 0; nt < 4; ++nt) {
#pragma unroll
      for (int kf = 0; kf < 4; ++kf) {
        bf8 pb = *(const bf8*)(Pb + (size_t)(nt * 16 + li) * 136 + kf * 32 + quad * 8);
#pragma unroll
        for (int ot = 0; ot < 2; ++ot) acc[ot][nt] = MFMA16(va[ot][kf], pb, acc[ot][nt]);
      }
    }
    // ---- S(t+1): writes pT[(t+1)&1] ----
    if (t < 15) {
      f4 civ4 = *(const f4*)(civS + mm2 + wv * 16 + quad * 4);
      short* Pw = &pT[(t + 1) & 1][0][0];
#pragma unroll
      for (int nt = 0; nt < 4; ++nt) {
        f4 s = {};
        s = MFMA16(a0, q[nt][0], s);
        s = MFMA16(a1, q[nt][1], s);
        short4 pv;
#pragma unroll
        for (int r = 0; r < 4; ++r) {
          float p = __expf(s[r]) * civ4[r];
          short ph = f2b(p);
          ((short*)&pv)[r] = ph;
          rloc[nt] += b2f(ph);
        }
        *(short4*)(Pw + (size_t)(nt * 16 + li) * 136 + wv * 16 + quad * 4) = pv;
      }
#pragma unroll
      for (int ot = 0; ot < 2; ++ot)
#pragma unroll
        for (int kf = 0; kf < 4; ++kf) va[ot][kf] = vn[ot][kf];
    }
    __syncthreads();
  }
  // ---- row-sum reduction: quad-shfl then cross-wave LDS atomics ----
#pragma unroll
  for (int nt = 0; nt < 4; ++nt) {
    float rv = rloc[nt];
    rv += __shfl_xor(rv, 16);
    rv += __shfl_xor(rv, 32);
    if (quad == 0) atomicAdd(&racc[nt * 16 + li], rv);
  }
  __syncthreads();
  // ---- epilogue: y = x - fsa / rsum ----
#pragma unroll
  for (int nt = 0; nt < 4; ++nt) {
    const int nn = n0 + nt * 16 + li;
    const float rinv = 1.f / (1e-9f + racc[nt * 16 + li]);
    short* yrow = yT + ((size_t)b * N_ + nn) * C_ + ob;
#pragma unroll
    for (int ot = 0; ot < 2; ++ot) {
      short4 v;
#pragma unroll
      for (int r = 0; r < 4; ++r) {
        int o = ob + ot * 16 + quad * 4 + r;
        float xv = x[((size_t)b * C_ + o) * N_ + nn];
        ((short*)&v)[r] = f2b(xv - acc[ot][nt][r] * rinv);
      }
      *(short4*)(yrow + ot * 16 + quad * 4) = v;
    }
  }
}

// ---------------- h = Wp . y -> H (=d_out) f32 + per-block BN partials ----------------
__global__ __launch_bounds__(256, 4) void wp_kernel(const short* __restrict__ yT,
                                                    const short* __restrict__ Wp,
                                                    float* __restrict__ H,
                                                    float* __restrict__ P1,
                                                    float* __restrict__ P2) {
  __shared__ alignas(16) float ha[64][68];
  __shared__ float red1[64][4];
  __shared__ float red2[64][4];
  const int tid = threadIdx.x;
  const int wv = tid >> 6, lane = tid & 63;
  const int li = lane & 15, quad = lane >> 4;
  const int b = blockIdx.y, n0 = blockIdx.x * 64, o0 = blockIdx.z * 64;
  const int n = n0 + wv * 16 + li;
  const short* yrow = yT + ((size_t)b * N_ + n) * C_ + quad * 8;
  f4 acc[4] = {};
  for (int ks = 0; ks < 8; ++ks) {
    bf8 bfr = *(const bf8*)(yrow + ks * 32);
#pragma unroll
    for (int ot = 0; ot < 4; ++ot) {
      bf8 afr = *(const bf8*)(Wp + (size_t)(o0 + ot * 16 + li) * C_ + ks * 32 + quad * 8);
      acc[ot] = MFMA16(afr, bfr, acc[ot]);
    }
  }
#pragma unroll
  for (int ot = 0; ot < 4; ++ot)
#pragma unroll
    for (int r = 0; r < 4; ++r) ha[ot * 16 + quad * 4 + r][wv * 16 + li] = acc[ot][r];
  __syncthreads();
  const int o = tid >> 2, nq = tid & 3;
  float s1p = 0.f, s2p = 0.f;
  float* hrow = H + ((size_t)b * C_ + o0 + o) * N_ + n0 + nq * 16;
#pragma unroll
  for (int j4 = 0; j4 < 4; ++j4) {
    float4 v = *reinterpret_cast<const float4*>(&ha[o][nq * 16 + j4 * 4]);
    s1p += v.x + v.y + v.z + v.w;
    s2p += v.x * v.x + v.y * v.y + v.z * v.z + v.w * v.w;
    reinterpret_cast<float4*>(hrow)[j4] = v;
  }
  red1[o][nq] = s1p;
  red2[o][nq] = s2p;
  __syncthreads();
  if (tid < 64) {
    float a1 = red1[tid][0] + red1[tid][1] + red1[tid][2] + red1[tid][3];
    float a2 = red2[tid][0] + red2[tid][1] + red2[tid][2] + red2[tid][3];
    const int g = b * 32 + blockIdx.x;
    P1[(size_t)g * 256 + o0 + tid] = a1;
    P2[(size_t)g * 256 + o0 + tid] = a2;
  }
}

// ---------------- fold partials: no atomics, direct write ----------------
// grid(16) x 256 thr: block owns 16 channels; 16 lanes per channel sum 512 groups.
__global__ __launch_bounds__(256) void bn_reduce_kernel(const float* __restrict__ P1,
                                                        const float* __restrict__ P2,
                                                        float* __restrict__ S1,
                                                        float* __restrict__ S2) {
  const int lc = threadIdx.x >> 4, gl = threadIdx.x & 15;
  const int c = blockIdx.x * 16 + lc;
  float a1 = 0.f, a2 = 0.f;
#pragma unroll
  for (int k = 0; k < 32; ++k) {
    int g = gl + k * 16;
    a1 += P1[(size_t)g * 256 + c];
    a2 += P2[(size_t)g * 256 + c];
  }
#pragma unroll
  for (int m = 1; m < 16; m <<= 1) {
    a1 += __shfl_xor(a1, m);
    a2 += __shfl_xor(a2, m);
  }
  if (gl == 0) {
    S1[c] = a1;
    S2[c] = a2;
  }
}

// ---------------- BN apply (affine terms computed inline from S1/S2) ----------------
__global__ __launch_bounds__(256) void bn_apply_kernel(const float* __restrict__ H,
                                                       const float* __restrict__ x,
                                                       const float* __restrict__ S1,
                                                       const float* __restrict__ S2,
                                                       const float* __restrict__ gamma,
                                                       const float* __restrict__ beta,
                                                       float* __restrict__ out) {
  size_t idx = ((size_t)blockIdx.x * 256 + threadIdx.x) * 4;
  int o = (int)((idx >> 11) & 255);
  const float invn = 1.f / ((float)B_ * N_);
  float mean = S1[o] * invn;
  float var = S2[o] * invn - mean * mean;
  float inv = rsqrtf(var + 1e-5f);
  float a = gamma[o] * inv;
  float c = beta[o] - mean * a;
  float4 h = *reinterpret_cast<const float4*>(&H[idx]);
  float4 xv = *reinterpret_cast<const float4*>(&x[idx]);
  float4 r;
  r.x = fmaxf(h.x * a + c, 0.f) + xv.x;
  r.y = fmaxf(h.y * a + c, 0.f) + xv.y;
  r.z = fmaxf(h.z * a + c, 0.f) + xv.z;
  r.w = fmaxf(h.w * a + c, 0.f) + xv.w;
  *reinterpret_cast<float4*>(&out[idx]) = r;
}

extern "C" void kernel_launch(void* const* d_in, const int* in_sizes, int n_in,
                              void* d_out, int out_size, void* d_ws, size_t ws_size,
                              hipStream_t stream) {
  (void)in_sizes; (void)n_in; (void)out_size; (void)ws_size;
  const float* x = (const float*)d_in[0];
  const float* Wq = (const float*)d_in[1];
  const float* Wk = (const float*)d_in[2];
  const float* Wv = (const float*)d_in[3];
  const float* Wp = (const float*)d_in[4];
  const float* gamma = (const float*)d_in[5];
  const float* beta = (const float*)d_in[6];
  char* ws = (char*)d_ws;
  short* xT = (short*)(ws + OFF_XT);
  short* Qn = (short*)(ws + OFF_QN);
  short* Kn = (short*)(ws + OFF_KN);
  short* Vt = (short*)(ws + OFF_VT);
  float* CI = (float*)(ws + OFF_CI);
  short* Wqb = (short*)(ws + OFF_WQ);
  short* Wkb = (short*)(ws + OFF_WK);
  short* Wvb = (short*)(ws + OFF_WV);
  short* Wpb = (short*)(ws + OFF_WP);
  float* S1 = (float*)(ws + OFF_S1);
  float* S2 = (float*)(ws + OFF_S2);
  float* P1 = (float*)(ws + OFF_P1);
  float* P2 = (float*)(ws + OFF_P2);
  short* yT = xT;            // reuse xT region (dead after projections)
  float* out = (float*)d_out;
  float* H = out;            // H staged in d_out; bn_apply rewrites in place

  dim3 blk(256);
  transpose_x_kernel<<<dim3(32, 4, 17), blk, 0, stream>>>(x, xT, Wq, Wk, Wv, Wp,
                                                          Wqb, Wkb, Wvb, Wpb);
  proj_qkv_kernel<<<dim3(32, 16, 2), blk, 0, stream>>>(xT, Wqb, Wkb, Wvb, Qn, Kn, Vt);
  colstats_kernel<<<dim3(32, 16), blk, 0, stream>>>(Qn, Kn, CI);
  attn_fsa_kernel<<<dim3(32, 16), dim3(512), 0, stream>>>(x, Qn, Kn, Vt, CI, yT);
  wp_kernel<<<dim3(32, 16, 4), blk, 0, stream>>>(yT, Wpb, H, P1, P2);
  bn_reduce_kernel<<<dim3(16), blk, 0, stream>>>(P1, P2, S1, S2);
  bn_apply_kernel<<<dim3(8192), blk, 0, stream>>>(H, x, S1, S2, gamma, beta, out);
}